// Round 1
// baseline (278.197 us; speedup 1.0000x reference)
//
#include <hip/hip_runtime.h>

// Problem: Fusin_Dice_rank — fused softmax + dice loss + top-30 rank hinge loss.
// B=32 samples, N=512*512=262144 elems/sample, K=30.
//
// Kernel A: one full pass over inputs. Per block (chunk of 4096 elems of one
//   sample): p1 = sigmoid(x1-x0); accumulate (sum p, sum t, sum p*t); exact
//   per-block top-30 of a=p*(1-t) and b=(1-p)*t via 30 rounds of block argmax
//   over register-resident values (u64 key = value_bits<<32 | uid).
// Kernel B: per sample, merge 64 blocks * 30 candidates -> exact top-30,
//   compute dice + 30x30 hinge sum.
// Kernel C: reduce 32 samples -> out[0]=loss_D, out[1]=loss_R.

#define N_ELEM (512 * 512)
#define B_SAMPLES 32
#define CHUNK 4096
#define BLOCKS_PER_S (N_ELEM / CHUNK)      // 64
#define TOPK 30
#define CAND_PER_S (BLOCKS_PER_S * TOPK)   // 1920

// ws layout (floats)
#define PART_OFF 0                                    // [32][64][3]
#define CANDA_OFF (B_SAMPLES * BLOCKS_PER_S * 3)      // 6144
#define CANDB_OFF (CANDA_OFF + B_SAMPLES * CAND_PER_S) // + 61440
#define SAMP_OFF (CANDB_OFF + B_SAMPLES * CAND_PER_S)  // [32][2]

__device__ __forceinline__ unsigned long long shflxor_u64(unsigned long long v, int off) {
    unsigned int lo = (unsigned int)v;
    unsigned int hi = (unsigned int)(v >> 32);
    lo = __shfl_xor(lo, off, 64);
    hi = __shfl_xor(hi, off, 64);
    return ((unsigned long long)hi << 32) | lo;
}

__device__ __forceinline__ unsigned long long packKey(float v, unsigned int uid) {
    // values are guaranteed >= 0 (or -1 after removal, clamped to 0 which is
    // tie-safe: re-selecting a removed slot can only happen when all remaining
    // true values are 0, in which case the selected value 0 is correct).
    return ((unsigned long long)__float_as_uint(fmaxf(v, 0.0f)) << 32) | uid;
}

__global__ __launch_bounds__(256) void passA(const float* __restrict__ pred,
                                             const float* __restrict__ tgt,
                                             float* __restrict__ ws) {
    const int s = blockIdx.x >> 6;        // sample
    const int c = blockIdx.x & 63;        // chunk within sample
    const int tid = threadIdx.x;
    const int lane = tid & 63;
    const int wid = tid >> 6;

    const float* x0p = pred + (size_t)s * 2 * N_ELEM + (size_t)c * CHUNK;
    const float* x1p = x0p + N_ELEM;
    const float* tp  = tgt + (size_t)s * N_ELEM + (size_t)c * CHUNK;

    float av[16], bv[16];
    float sp = 0.f, st = 0.f, spt = 0.f;

#pragma unroll
    for (int j = 0; j < 4; ++j) {
        float4 X0 = ((const float4*)x0p)[j * 256 + tid];
        float4 X1 = ((const float4*)x1p)[j * 256 + tid];
        float4 T  = ((const float4*)tp )[j * 256 + tid];
#define PROC(q, xx0, xx1, tt)                                      \
        {                                                          \
            float p = 1.0f / (1.0f + __expf((xx0) - (xx1)));       \
            float t = (tt);                                        \
            sp += p; st += t; spt += p * t;                        \
            av[j * 4 + (q)] = p * (1.0f - t);                      \
            bv[j * 4 + (q)] = (1.0f - p) * t;                      \
        }
        PROC(0, X0.x, X1.x, T.x)
        PROC(1, X0.y, X1.y, T.y)
        PROC(2, X0.z, X1.z, T.z)
        PROC(3, X0.w, X1.w, T.w)
#undef PROC
    }

    __shared__ float red[4 * 4];
    __shared__ unsigned long long sredA[4], sredB[4];

    // ---- dice partial sums ----
    for (int off = 32; off; off >>= 1) {
        sp  += __shfl_xor(sp, off, 64);
        st  += __shfl_xor(st, off, 64);
        spt += __shfl_xor(spt, off, 64);
    }
    if (lane == 0) { red[wid * 4 + 0] = sp; red[wid * 4 + 1] = st; red[wid * 4 + 2] = spt; }
    __syncthreads();
    if (tid == 0) {
        float a = 0.f, b = 0.f, cc = 0.f;
#pragma unroll
        for (int w = 0; w < 4; ++w) { a += red[w * 4]; b += red[w * 4 + 1]; cc += red[w * 4 + 2]; }
        float* part = ws + PART_OFF + (size_t)(s * BLOCKS_PER_S + c) * 3;
        part[0] = a; part[1] = b; part[2] = cc;
    }

    // ---- per-block exact top-30 of av and bv (30 rounds of block argmax) ----
    float* candA = ws + CANDA_OFF + (size_t)(s * BLOCKS_PER_S + c) * TOPK;
    float* candB = ws + CANDB_OFF + (size_t)(s * BLOCKS_PER_S + c) * TOPK;

    for (int k = 0; k < TOPK; ++k) {
        unsigned long long ka = 0ull, kb = 0ull;
#pragma unroll
        for (int e = 0; e < 16; ++e) {
            unsigned int uid = (unsigned int)(tid + e * 256);  // unique in [0,4096)
            unsigned long long pa = packKey(av[e], uid);
            if (pa > ka) ka = pa;
            unsigned long long pb = packKey(bv[e], uid);
            if (pb > kb) kb = pb;
        }
        for (int off = 32; off; off >>= 1) {
            unsigned long long oa = shflxor_u64(ka, off);
            if (oa > ka) ka = oa;
            unsigned long long ob = shflxor_u64(kb, off);
            if (ob > kb) kb = ob;
        }
        if (lane == 0) { sredA[wid] = ka; sredB[wid] = kb; }
        __syncthreads();
        ka = sredA[0]; kb = sredB[0];
#pragma unroll
        for (int w = 1; w < 4; ++w) {
            if (sredA[w] > ka) ka = sredA[w];
            if (sredB[w] > kb) kb = sredB[w];
        }
        __syncthreads();  // protect sred for next round

        if (tid == 0) {
            candA[k] = __uint_as_float((unsigned int)(ka >> 32));
            candB[k] = __uint_as_float((unsigned int)(kb >> 32));
        }
        // remove the selected instance (exactly one owner thread/slot each)
        unsigned int ua = (unsigned int)ka;
        if ((ua & 255u) == (unsigned int)tid) {
            int slot = (int)(ua >> 8);
#pragma unroll
            for (int e = 0; e < 16; ++e) if (e == slot) av[e] = -1.0f;
        }
        unsigned int ub = (unsigned int)kb;
        if ((ub & 255u) == (unsigned int)tid) {
            int slot = (int)(ub >> 8);
#pragma unroll
            for (int e = 0; e < 16; ++e) if (e == slot) bv[e] = -1.0f;
        }
    }
}

__global__ __launch_bounds__(256) void passB(float* __restrict__ ws) {
    const int s = blockIdx.x;
    const int tid = threadIdx.x;
    const int lane = tid & 63;
    const int wid = tid >> 6;

    __shared__ float ntop[TOPK], pv[TOPK];
    __shared__ unsigned long long sred[4];
    __shared__ float fred[4 * 4];

    // ---- dice sums over 64 chunk partials ----
    float sp = 0.f, st = 0.f, spt = 0.f;
    if (tid < BLOCKS_PER_S) {
        const float* part = ws + PART_OFF + (size_t)(s * BLOCKS_PER_S + tid) * 3;
        sp = part[0]; st = part[1]; spt = part[2];
    }
    for (int off = 32; off; off >>= 1) {
        sp  += __shfl_xor(sp, off, 64);
        st  += __shfl_xor(st, off, 64);
        spt += __shfl_xor(spt, off, 64);
    }
    if (lane == 0) { fred[wid * 4 + 0] = sp; fred[wid * 4 + 1] = st; fred[wid * 4 + 2] = spt; }
    __syncthreads();

    // ---- exact top-30 over 1920 candidates, for A then B ----
    for (int arr = 0; arr < 2; ++arr) {
        const float* cand = ws + (arr == 0 ? CANDA_OFF : CANDB_OFF) + (size_t)s * CAND_PER_S;
        float v[8];
#pragma unroll
        for (int e = 0; e < 8; ++e) {
            int idx = tid + e * 256;
            v[e] = (idx < CAND_PER_S) ? cand[idx] : 0.0f;  // pad 0 is tie-safe (values >= 0)
        }
        for (int k = 0; k < TOPK; ++k) {
            unsigned long long kk = 0ull;
#pragma unroll
            for (int e = 0; e < 8; ++e) {
                unsigned long long p = packKey(v[e], (unsigned int)(tid + e * 256));
                if (p > kk) kk = p;
            }
            for (int off = 32; off; off >>= 1) {
                unsigned long long o = shflxor_u64(kk, off);
                if (o > kk) kk = o;
            }
            if (lane == 0) sred[wid] = kk;
            __syncthreads();
            kk = sred[0];
#pragma unroll
            for (int w = 1; w < 4; ++w) if (sred[w] > kk) kk = sred[w];
            __syncthreads();
            if (tid == 0) {
                float val = __uint_as_float((unsigned int)(kk >> 32));
                if (arr == 0) ntop[k] = val; else pv[k] = val;
            }
            unsigned int u = (unsigned int)kk;
            if ((u & 255u) == (unsigned int)tid) {
                int slot = (int)(u >> 8);
#pragma unroll
                for (int e = 0; e < 8; ++e) if (e == slot) v[e] = -1.0f;
            }
        }
    }
    __syncthreads();  // make ntop/pv visible

    // ---- 30x30 hinge sum ----
    float rs = 0.f;
    for (int p = tid; p < TOPK * TOPK; p += 256) {
        int i = p / TOPK, j = p - i * TOPK;
        float th = ntop[i] - (1.0f - pv[j]) + 0.3f;
        rs += fmaxf(th, 0.0f);
    }
    for (int off = 32; off; off >>= 1) rs += __shfl_xor(rs, off, 64);
    if (lane == 0) fred[wid * 4 + 3] = rs;
    __syncthreads();

    if (tid == 0) {
        float SP = 0.f, ST = 0.f, SPT = 0.f, RS = 0.f;
#pragma unroll
        for (int w = 0; w < 4; ++w) {
            SP += fred[w * 4]; ST += fred[w * 4 + 1]; SPT += fred[w * 4 + 2]; RS += fred[w * 4 + 3];
        }
        const float Nf = (float)N_ELEM;
        float dice1 = 1.0f - 2.0f * SPT / (SP + ST + 1e-5f);
        float dice0 = 1.0f - 2.0f * (Nf - SP - ST + SPT) / ((Nf - SP) + (Nf - ST) + 1e-5f);
        float* samp = ws + SAMP_OFF + s * 2;
        samp[0] = dice0 + dice1;
        samp[1] = RS;
    }
}

__global__ __launch_bounds__(64) void passC(const float* __restrict__ ws, float* __restrict__ out) {
    const int tid = threadIdx.x;
    float d = 0.f, r = 0.f;
    if (tid < B_SAMPLES) {
        d = ws[SAMP_OFF + tid * 2 + 0];
        r = ws[SAMP_OFF + tid * 2 + 1];
    }
    for (int off = 32; off; off >>= 1) {
        d += __shfl_xor(d, off, 64);
        r += __shfl_xor(r, off, 64);
    }
    if (tid == 0) {
        out[0] = d * (1.0f / (2.0f * B_SAMPLES));            // (mean d0 + mean d1)/2
        out[1] = r * (1.0f / (B_SAMPLES * TOPK * TOPK));     // global mean of hinge
    }
}

extern "C" void kernel_launch(void* const* d_in, const int* in_sizes, int n_in,
                              void* d_out, int out_size, void* d_ws, size_t ws_size,
                              hipStream_t stream) {
    (void)in_sizes; (void)n_in; (void)out_size; (void)ws_size;
    const float* pred = (const float*)d_in[0];   // [32,2,512,512] f32
    const float* tgt  = (const float*)d_in[1];   // [32,512,512]  f32
    float* ws  = (float*)d_ws;
    float* out = (float*)d_out;

    passA<<<B_SAMPLES * BLOCKS_PER_S, 256, 0, stream>>>(pred, tgt, ws);
    passB<<<B_SAMPLES, 256, 0, stream>>>(ws);
    passC<<<1, 64, 0, stream>>>(ws, out);
}

// Round 2
// 261.248 us; speedup vs baseline: 1.0649x; 1.0649x over previous
//
#include <hip/hip_runtime.h>

// Fusin_Dice_rank: fused 2-ch softmax + dice + top-30 rank hinge.
// Strategy: select on order-preserving u32 keys of d = x1-x0 (monotone with
// p = sigmoid(d)).  passA: dice partial sums + per-block candidate superset of
// top-30 via 1024-bin LDS histogram threshold (exact fallback on overflow).
// passB: per-sample exact 4-level radix select over ~3k candidates + hinge +
// dice finalize; last finishing block reduces 32 samples -> out.

#define N_ELEM (512 * 512)
#define B_SAMPLES 32
#define CHUNK 4096
#define BLOCKS_PER_S 64
#define TOPK 30
#define CAP 128
#define BINS 1024

// ws layout in 4-byte units
#define PART_OFF 0                                           // [32][64][3] f32
#define CNTA_OFF (PART_OFF + B_SAMPLES * BLOCKS_PER_S * 3)   // [2048] u32
#define CNTB_OFF (CNTA_OFF + B_SAMPLES * BLOCKS_PER_S)
#define CANDA_OFF (CNTB_OFF + B_SAMPLES * BLOCKS_PER_S)      // [2048][128] u32
#define CANDB_OFF (CANDA_OFF + B_SAMPLES * BLOCKS_PER_S * CAP)
#define SAMP_OFF (CANDB_OFF + B_SAMPLES * BLOCKS_PER_S * CAP) // [32][2] f32
#define DONE_OFF (SAMP_OFF + B_SAMPLES * 2)                   // [1] u32

__device__ __forceinline__ unsigned ordf(float f) {
    unsigned u = __float_as_uint(f);
    return (u & 0x80000000u) ? ~u : (u | 0x80000000u);
}

__device__ __forceinline__ float invord_sigmoid(unsigned u) {
    // value = sigmoid(f) where u = ordf(f); u==0 is the "no value" placeholder
    if (u == 0u) return 0.0f;
    unsigned b = (u & 0x80000000u) ? (u ^ 0x80000000u) : ~u;
    float f = __uint_as_float(b);
    return 1.0f / (1.0f + __expf(-f));
}

__device__ __forceinline__ unsigned long long shflxor_u64(unsigned long long v, int off) {
    unsigned lo = (unsigned)v, hi = (unsigned)(v >> 32);
    lo = __shfl_xor(lo, off, 64);
    hi = __shfl_xor(hi, off, 64);
    return ((unsigned long long)hi << 32) | lo;
}

// Emit a superset of the block's top-30 keys (by value) from k[16]/thread.
// Exact-fallback guarantees correctness if the histogram superset overflows CAP.
__device__ __forceinline__ void select_emit(unsigned (&k)[16], unsigned* dst,
                                            unsigned* cntp, int tid, int lane, int wid,
                                            int* hist, int* wtot, int* shBt, int* shCnt,
                                            unsigned long long* sred) {
    for (int i = tid; i < BINS; i += 256) hist[i] = 0;
    if (tid == 0) { *shBt = 0; *shCnt = 0; }
    __syncthreads();
#pragma unroll
    for (int e = 0; e < 16; ++e) {
        unsigned u = k[e];
        if (u) atomicAdd(&hist[u >> 22], 1);
    }
    __syncthreads();
    int c0 = hist[4 * tid], c1 = hist[4 * tid + 1], c2 = hist[4 * tid + 2], c3 = hist[4 * tid + 3];
    int suf = c0 + c1 + c2 + c3;
#pragma unroll
    for (int off = 1; off < 64; off <<= 1) {
        int v = __shfl_down(suf, off, 64);
        if (lane + off < 64) suf += v;
    }
    if (lane == 0) wtot[wid] = suf;
    __syncthreads();
    int S = suf;
    for (int w = wid + 1; w < 4; ++w) S += wtot[w];
    // bins 4t..4t+3 have suffix counts S, S-c0, S-c0-c1, S-c0-c1-c2
    {
        int sfx = S;
        int cc[4] = {c0, c1, c2, c3};
#pragma unroll
        for (int q = 0; q < 4; ++q) {
            int cnt = cc[q];
            if (sfx >= TOPK && sfx - cnt < TOPK) *shBt = 4 * tid + q;
            sfx -= cnt;
        }
    }
    __syncthreads();
    int bt = *shBt;
#pragma unroll
    for (int e = 0; e < 16; ++e) {
        unsigned u = k[e];
        if (u && (int)(u >> 22) >= bt) {
            int pos = atomicAdd(shCnt, 1);
            if (pos < CAP) dst[pos] = u;
        }
    }
    __syncthreads();
    int n = *shCnt;
    if (n > CAP) {
        // exact top-30 (never expected on benchmark data)
        for (int r = 0; r < TOPK; ++r) {
            unsigned long long best = 0ull;
#pragma unroll
            for (int e = 0; e < 16; ++e) {
                unsigned long long p = ((unsigned long long)k[e] << 32) | (unsigned)(tid * 16 + e);
                if (p > best) best = p;
            }
            for (int off = 32; off; off >>= 1) {
                unsigned long long o = shflxor_u64(best, off);
                if (o > best) best = o;
            }
            if (lane == 0) sred[wid] = best;
            __syncthreads();
            best = sred[0];
#pragma unroll
            for (int w = 1; w < 4; ++w) if (sred[w] > best) best = sred[w];
            __syncthreads();
            if (tid == 0) dst[r] = (unsigned)(best >> 32);
            unsigned uid = (unsigned)best;
            if ((int)(uid >> 4) == tid) {
#pragma unroll
                for (int e = 0; e < 16; ++e) if (e == (int)(uid & 15u)) k[e] = 0u;
            }
        }
        n = TOPK;
    }
    if (tid == 0) *cntp = (unsigned)n;
}

__global__ __launch_bounds__(256) void passA(const float* __restrict__ pred,
                                             const float* __restrict__ tgt,
                                             float* __restrict__ wsf) {
    unsigned* wsu = (unsigned*)wsf;
    const int s = blockIdx.x >> 6, c = blockIdx.x & 63;
    const int tid = threadIdx.x, lane = tid & 63, wid = tid >> 6;

    if (blockIdx.x == 0 && tid == 0) wsu[DONE_OFF] = 0u;  // for passB last-block

    const float* x0p = pred + (size_t)s * 2 * N_ELEM + (size_t)c * CHUNK;
    const float* x1p = x0p + N_ELEM;
    const float* tp  = tgt + (size_t)s * N_ELEM + (size_t)c * CHUNK;

    unsigned ka[16], kb[16];
    float sp = 0.f, st = 0.f, spt = 0.f;

#pragma unroll
    for (int j = 0; j < 4; ++j) {
        float4 X0 = ((const float4*)x0p)[j * 256 + tid];
        float4 X1 = ((const float4*)x1p)[j * 256 + tid];
        float4 T  = ((const float4*)tp )[j * 256 + tid];
#define PROC(q, xx0, xx1, tt)                                     \
        {                                                         \
            float p = 1.0f / (1.0f + __expf((xx0) - (xx1)));      \
            float t = (tt);                                       \
            sp += p; st += t; spt += p * t;                       \
            unsigned o = ordf((xx1) - (xx0));                     \
            bool t1 = (t != 0.0f);                                \
            ka[j * 4 + (q)] = t1 ? 0u : o;                        \
            kb[j * 4 + (q)] = t1 ? ~o : 0u;                       \
        }
        PROC(0, X0.x, X1.x, T.x)
        PROC(1, X0.y, X1.y, T.y)
        PROC(2, X0.z, X1.z, T.z)
        PROC(3, X0.w, X1.w, T.w)
#undef PROC
    }

    __shared__ int hist[BINS];
    __shared__ int wtot[4];
    __shared__ int shBt, shCnt;
    __shared__ float red[16];
    __shared__ unsigned long long sred[4];

    // dice partial sums
    for (int off = 32; off; off >>= 1) {
        sp  += __shfl_xor(sp, off, 64);
        st  += __shfl_xor(st, off, 64);
        spt += __shfl_xor(spt, off, 64);
    }
    if (lane == 0) { red[wid * 4] = sp; red[wid * 4 + 1] = st; red[wid * 4 + 2] = spt; }
    __syncthreads();
    if (tid == 0) {
        float a = 0.f, b = 0.f, cc = 0.f;
#pragma unroll
        for (int w = 0; w < 4; ++w) { a += red[w * 4]; b += red[w * 4 + 1]; cc += red[w * 4 + 2]; }
        float* part = wsf + PART_OFF + (size_t)(s * BLOCKS_PER_S + c) * 3;
        part[0] = a; part[1] = b; part[2] = cc;
    }
    __syncthreads();

    const int blk = s * BLOCKS_PER_S + c;
    select_emit(ka, wsu + CANDA_OFF + (size_t)blk * CAP, wsu + CNTA_OFF + blk,
                tid, lane, wid, hist, wtot, &shBt, &shCnt, sred);
    __syncthreads();
    select_emit(kb, wsu + CANDB_OFF + (size_t)blk * CAP, wsu + CNTB_OFF + blk,
                tid, lane, wid, hist, wtot, &shBt, &shCnt, sred);
}

__global__ __launch_bounds__(256) void passB(float* __restrict__ wsf, float* __restrict__ out) {
    unsigned* wsu = (unsigned*)wsf;
    const int s = blockIdx.x;
    const int tid = threadIdx.x, lane = tid & 63, wid = tid >> 6;

    __shared__ unsigned L[BLOCKS_PER_S * CAP];  // 32 KB
    __shared__ int hist[BINS];
    __shared__ int wtot[4];
    __shared__ int cn[64], pf[64];
    __shared__ int shN, shBt, shChi, shCntBt, shK, shR, shResolved, shDone;
    __shared__ unsigned R[TOPK];
    __shared__ float ntop[TOPK], pv[TOPK];
    __shared__ float fred[8];

    // dice sums over 64 chunk partials (wave 0 covers all 64)
    {
        float sp = 0.f, st = 0.f, spt = 0.f;
        if (tid < 64) {
            const float* part = wsf + PART_OFF + (size_t)(s * BLOCKS_PER_S + tid) * 3;
            sp = part[0]; st = part[1]; spt = part[2];
        }
        for (int off = 32; off; off >>= 1) {
            sp  += __shfl_xor(sp, off, 64);
            st  += __shfl_xor(st, off, 64);
            spt += __shfl_xor(spt, off, 64);
        }
        if (tid == 0) { fred[0] = sp; fred[1] = st; fred[2] = spt; }
    }

    for (int arr = 0; arr < 2; ++arr) {
        unsigned* cntArr  = wsu + (arr ? CNTB_OFF : CNTA_OFF) + s * BLOCKS_PER_S;
        unsigned* candArr = wsu + (arr ? CANDB_OFF : CANDA_OFF) + (size_t)s * BLOCKS_PER_S * CAP;

        if (tid < 64) {
            int cv = (int)cntArr[tid];
            int pe = cv;
#pragma unroll
            for (int off = 1; off < 64; off <<= 1) {
                int v = __shfl_up(pe, off, 64);
                if (lane >= off) pe += v;
            }
            cn[tid] = cv; pf[tid] = pe - cv;
            if (tid == 63) shN = pe;
        }
        __syncthreads();
        const int n = shN;
        for (int b = 0; b < 64; ++b) {
            int nb = cn[b], off0 = pf[b];
            for (int i = tid; i < nb; i += 256) L[off0 + i] = candArr[b * CAP + i];
        }
        if (tid == 0) { shK = TOPK; shR = 0; shResolved = 0; }
        __syncthreads();

        unsigned prefix = 0u, himask = 0u;
        const int shifts[4] = {22, 12, 2, 0};
        const unsigned bmask[4] = {1023u, 1023u, 1023u, 3u};
#pragma unroll
        for (int lev = 0; lev < 4; ++lev) {
            if (!shResolved) {  // block-uniform
                const int shift = shifts[lev];
                const unsigned bm = bmask[lev];
                for (int i = tid; i < BINS; i += 256) hist[i] = 0;
                __syncthreads();
                for (int i = tid; i < n; i += 256) {
                    unsigned u = L[i];
                    if ((u & himask) == prefix) atomicAdd(&hist[(u >> shift) & bm], 1);
                }
                __syncthreads();
                const int K = shK;
                int c0 = hist[4 * tid], c1 = hist[4 * tid + 1], c2 = hist[4 * tid + 2], c3 = hist[4 * tid + 3];
                int suf = c0 + c1 + c2 + c3;
#pragma unroll
                for (int off = 1; off < 64; off <<= 1) {
                    int v = __shfl_down(suf, off, 64);
                    if (lane + off < 64) suf += v;
                }
                if (lane == 0) wtot[wid] = suf;
                if (tid == 0) shBt = -1;
                __syncthreads();
                int S = suf;
                for (int w = wid + 1; w < 4; ++w) S += wtot[w];
                {
                    int sfx = S;
                    int cc[4] = {c0, c1, c2, c3};
#pragma unroll
                    for (int q = 0; q < 4; ++q) {
                        int cnt = cc[q];
                        if (sfx >= K && sfx - cnt < K) { shBt = 4 * tid + q; shChi = sfx - cnt; shCntBt = cnt; }
                        sfx -= cnt;
                    }
                }
                __syncthreads();
                const int bt = shBt;
                if (bt < 0) {
                    // fewer than K active values: emit them all (practically unreachable)
                    for (int i = tid; i < n; i += 256) {
                        unsigned u = L[i];
                        if ((u & himask) == prefix) {
                            int pos = atomicAdd(&shR, 1);
                            if (pos < TOPK) R[pos] = u;
                        }
                    }
                    __syncthreads();
                    if (tid == 0) shResolved = 1;
                    __syncthreads();
                } else {
                    const int chi = shChi, cntbt = shCntBt;
                    const int Knew = K - chi;
                    const int finish = (cntbt == Knew) ? 1 : 0;
                    for (int i = tid; i < n; i += 256) {
                        unsigned u = L[i];
                        if ((u & himask) == prefix) {
                            int b_ = (int)((u >> shift) & bm);
                            if (b_ > bt || (finish && b_ == bt)) {
                                int pos = atomicAdd(&shR, 1);
                                R[pos] = u;
                            }
                        }
                    }
                    __syncthreads();
                    if (finish) {
                        if (tid == 0) shResolved = 1;
                    } else if (lev == 3) {
                        // exact-value tie at the boundary: append Knew copies
                        unsigned ustar = prefix | (unsigned)bt;
                        if (tid < Knew) { int pos = atomicAdd(&shR, 1); R[pos] = ustar; }
                        if (tid == 0) shResolved = 1;
                    } else {
                        if (tid == 0) shK = Knew;
                        prefix |= ((unsigned)bt << shift);
                        himask |= (bm << shift);
                    }
                    __syncthreads();
                }
            }
        }
        __syncthreads();
        const int rc = shR;
        if (tid < TOPK) {
            unsigned u = (tid < rc) ? R[tid] : 0u;
            float v = invord_sigmoid(u);
            if (arr) pv[tid] = v; else ntop[tid] = v;
        }
        __syncthreads();
    }

    // 30x30 hinge sum
    float rs = 0.f;
    for (int pch = tid; pch < TOPK * TOPK; pch += 256) {
        int i = pch / TOPK, j = pch - i * TOPK;
        float th = ntop[i] - (1.0f - pv[j]) + 0.3f;
        rs += fmaxf(th, 0.0f);
    }
    for (int off = 32; off; off >>= 1) rs += __shfl_xor(rs, off, 64);
    if (lane == 0) fred[4 + wid] = rs;
    __syncthreads();

    if (tid == 0) {
        float SP = fred[0], ST = fred[1], SPT = fred[2];
        float RS = fred[4] + fred[5] + fred[6] + fred[7];
        const float Nf = (float)N_ELEM;
        float dice1 = 1.0f - 2.0f * SPT / (SP + ST + 1e-5f);
        float dice0 = 1.0f - 2.0f * (Nf - SP - ST + SPT) / ((Nf - SP) + (Nf - ST) + 1e-5f);
        float* samp = wsf + SAMP_OFF + s * 2;
        samp[0] = dice0 + dice1;
        samp[1] = RS;
    }
    __threadfence();
    if (tid == 0) shDone = atomicAdd((int*)&wsu[DONE_OFF], 1);
    __syncthreads();
    if (shDone == B_SAMPLES - 1) {
        __threadfence();
        float d = 0.f, r = 0.f;
        if (tid < B_SAMPLES) {
            d = wsf[SAMP_OFF + tid * 2 + 0];
            r = wsf[SAMP_OFF + tid * 2 + 1];
        }
        for (int off = 32; off; off >>= 1) {
            d += __shfl_xor(d, off, 64);
            r += __shfl_xor(r, off, 64);
        }
        if (tid == 0) {
            out[0] = d * (1.0f / (2.0f * B_SAMPLES));
            out[1] = r * (1.0f / (B_SAMPLES * TOPK * TOPK));
        }
    }
}

extern "C" void kernel_launch(void* const* d_in, const int* in_sizes, int n_in,
                              void* d_out, int out_size, void* d_ws, size_t ws_size,
                              hipStream_t stream) {
    (void)in_sizes; (void)n_in; (void)out_size; (void)ws_size;
    const float* pred = (const float*)d_in[0];
    const float* tgt  = (const float*)d_in[1];
    float* wsf = (float*)d_ws;
    float* out = (float*)d_out;

    passA<<<B_SAMPLES * BLOCKS_PER_S, 256, 0, stream>>>(pred, tgt, wsf);
    passB<<<B_SAMPLES, 256, 0, stream>>>(wsf, out);
}

// Round 3
// 201.006 us; speedup vs baseline: 1.3840x; 1.2997x over previous
//
#include <hip/hip_runtime.h>

// Fusin_Dice_rank: fused 2-ch softmax + dice + top-30 rank hinge.
// Keys: order-preserving u32 ord(d), d = x1-x0 (monotone with p=sigmoid(d)).
// t is binary -> each element feeds exactly ONE of the two top-k problems:
//   A (t==0): key o=ordf(d); B (t==1): key ~o = ordf(-d).
// passA: dice partials + single fused dual-histogram threshold select,
//        emits per-block top-30 superset (exact fallback if > CAP).
// passB: per-sample parallel gather + exact 4-level radix select + hinge +
//        dice finalize; last finishing block reduces 32 samples -> out.

#define N_ELEM (512 * 512)
#define B_SAMPLES 32
#define CHUNK 4096
#define BLOCKS_PER_S 64
#define TOPK 30
#define CAP 96
#define BINS 1024

// ws layout in 4-byte units
#define PART_OFF 0                                            // [32][64][3] f32
#define CNTA_OFF (PART_OFF + B_SAMPLES * BLOCKS_PER_S * 3)    // [2048] u32
#define CNTB_OFF (CNTA_OFF + B_SAMPLES * BLOCKS_PER_S)
#define CANDA_OFF (CNTB_OFF + B_SAMPLES * BLOCKS_PER_S)       // [2048][CAP] u32
#define CANDB_OFF (CANDA_OFF + B_SAMPLES * BLOCKS_PER_S * CAP)
#define SAMP_OFF (CANDB_OFF + B_SAMPLES * BLOCKS_PER_S * CAP) // [32][2] f32
#define DONE_OFF (SAMP_OFF + B_SAMPLES * 2)                   // [1] u32

__device__ __forceinline__ unsigned ordf(float f) {
    unsigned u = __float_as_uint(f);
    return (u & 0x80000000u) ? ~u : (u | 0x80000000u);
}

__device__ __forceinline__ float invord_sigmoid(unsigned u) {
    // value = sigmoid(f) where u = ordf(f); u==0 is the "no value" placeholder
    if (u == 0u) return 0.0f;
    unsigned b = (u & 0x80000000u) ? (u ^ 0x80000000u) : ~u;
    float f = __uint_as_float(b);
    return 1.0f / (1.0f + __expf(-f));
}

__device__ __forceinline__ unsigned long long shflxor_u64(unsigned long long v, int off) {
    unsigned lo = (unsigned)v, hi = (unsigned)(v >> 32);
    lo = __shfl_xor(lo, off, 64);
    hi = __shfl_xor(hi, off, 64);
    return ((unsigned long long)hi << 32) | lo;
}

// Exact block top-30 (fallback, block-uniform call; never expected on bench data).
__device__ __forceinline__ void exact30(const unsigned (&o)[16], unsigned tmask, int isB,
                                        unsigned* dst, int tid, int lane, int wid,
                                        unsigned long long* sred) {
    unsigned rem = 0u;
    for (int r = 0; r < TOPK; ++r) {
        unsigned long long best = 0ull;
#pragma unroll
        for (int e = 0; e < 16; ++e) {
            unsigned t1 = (tmask >> e) & 1u;
            unsigned dead = (rem >> e) & 1u;
            unsigned key;
            if (isB) key = (t1 && !dead) ? ~o[e] : 0u;
            else     key = (!t1 && !dead) ? o[e] : 0u;
            unsigned long long p = ((unsigned long long)key << 32) | (unsigned)(tid * 16 + e);
            if (p > best) best = p;
        }
        for (int off = 32; off; off >>= 1) {
            unsigned long long v = shflxor_u64(best, off);
            if (v > best) best = v;
        }
        if (lane == 0) sred[wid] = best;
        __syncthreads();
        unsigned long long b0 = sred[0];
#pragma unroll
        for (int w = 1; w < 4; ++w) if (sred[w] > b0) b0 = sred[w];
        __syncthreads();
        if (tid == 0) dst[r] = (unsigned)(b0 >> 32);
        unsigned uid = (unsigned)b0;
        if ((int)(uid >> 4) == tid) rem |= 1u << (uid & 15u);
    }
}

__global__ __launch_bounds__(256) void passA(const float* __restrict__ pred,
                                             const float* __restrict__ tgt,
                                             float* __restrict__ wsf) {
    unsigned* wsu = (unsigned*)wsf;
    const int s = blockIdx.x >> 6, c = blockIdx.x & 63;
    const int tid = threadIdx.x, lane = tid & 63, wid = tid >> 6;

    if (blockIdx.x == 0 && tid == 0) wsu[DONE_OFF] = 0u;  // consumed only by passB

    const float* x0p = pred + (size_t)s * 2 * N_ELEM + (size_t)c * CHUNK;
    const float* x1p = x0p + N_ELEM;
    const float* tp  = tgt + (size_t)s * N_ELEM + (size_t)c * CHUNK;

    unsigned o[16];
    unsigned tmask = 0u;
    float sp = 0.f, spt = 0.f;

#pragma unroll
    for (int j = 0; j < 4; ++j) {
        float4 X0 = ((const float4*)x0p)[j * 256 + tid];
        float4 X1 = ((const float4*)x1p)[j * 256 + tid];
        float4 T  = ((const float4*)tp )[j * 256 + tid];
#define PROC(q, xx0, xx1, tt)                                  \
        {                                                      \
            float d = (xx1) - (xx0);                           \
            float p = 1.0f / (1.0f + __expf(-d));              \
            sp += p; spt = fmaf(p, (tt), spt);                 \
            o[j * 4 + (q)] = ordf(d);                          \
            if ((tt) != 0.0f) tmask |= 1u << (j * 4 + (q));    \
        }
        PROC(0, X0.x, X1.x, T.x)
        PROC(1, X0.y, X1.y, T.y)
        PROC(2, X0.z, X1.z, T.z)
        PROC(3, X0.w, X1.w, T.w)
#undef PROC
    }
    float st = (float)__popc(tmask);

    __shared__ int hist[2 * BINS];
    __shared__ float red[12];
    __shared__ int wtot[8];
    __shared__ int shBtA, shBtB, shCntA, shCntB;
    __shared__ unsigned long long sred[4];

    // dice partial sums (wave reduce, no sync needed before the hist-zero sync)
    for (int off = 32; off; off >>= 1) {
        sp  += __shfl_xor(sp, off, 64);
        st  += __shfl_xor(st, off, 64);
        spt += __shfl_xor(spt, off, 64);
    }
    if (lane == 0) { red[wid * 3] = sp; red[wid * 3 + 1] = st; red[wid * 3 + 2] = spt; }

    for (int i = tid; i < 2 * BINS; i += 256) hist[i] = 0;
    if (tid == 0) { shBtA = 0; shBtB = 0; shCntA = 0; shCntB = 0; }
    __syncthreads();

    if (tid == 0) {  // finalize dice partials while others start atomics
        float a = 0.f, b = 0.f, cc = 0.f;
#pragma unroll
        for (int w = 0; w < 4; ++w) { a += red[w * 3]; b += red[w * 3 + 1]; cc += red[w * 3 + 2]; }
        float* part = wsf + PART_OFF + (size_t)(s * BLOCKS_PER_S + c) * 3;
        part[0] = a; part[1] = b; part[2] = cc;
    }

    // fused dual histogram: each element feeds exactly one histogram
#pragma unroll
    for (int e = 0; e < 16; ++e) {
        unsigned b = o[e] >> 22;
        int bin = ((tmask >> e) & 1u) ? (int)(BINS + (b ^ 1023u)) : (int)b;
        atomicAdd(&hist[bin], 1);
    }
    __syncthreads();

    // dual suffix scan: thread owns A bins 4t..4t+3 and B bins 1024+4t..
    int c0 = hist[4 * tid], c1 = hist[4 * tid + 1], c2 = hist[4 * tid + 2], c3 = hist[4 * tid + 3];
    int d0 = hist[BINS + 4 * tid], d1 = hist[BINS + 4 * tid + 1],
        d2 = hist[BINS + 4 * tid + 2], d3 = hist[BINS + 4 * tid + 3];
    int sufA = c0 + c1 + c2 + c3, sufB = d0 + d1 + d2 + d3;
#pragma unroll
    for (int off = 1; off < 64; off <<= 1) {
        int vA = __shfl_down(sufA, off, 64);
        int vB = __shfl_down(sufB, off, 64);
        if (lane + off < 64) { sufA += vA; sufB += vB; }
    }
    if (lane == 0) { wtot[wid] = sufA; wtot[4 + wid] = sufB; }
    __syncthreads();
    int SA = sufA, SB = sufB;
    for (int w = wid + 1; w < 4; ++w) { SA += wtot[w]; SB += wtot[4 + w]; }
    {
        int sfx = SA; int cc[4] = {c0, c1, c2, c3};
#pragma unroll
        for (int q = 0; q < 4; ++q) { if (sfx >= TOPK && sfx - cc[q] < TOPK) shBtA = 4 * tid + q; sfx -= cc[q]; }
        sfx = SB; int dd[4] = {d0, d1, d2, d3};
#pragma unroll
        for (int q = 0; q < 4; ++q) { if (sfx >= TOPK && sfx - dd[q] < TOPK) shBtB = 4 * tid + q; sfx -= dd[q]; }
    }
    __syncthreads();

    const int btA = shBtA, btB = shBtB;
    const int blk = s * BLOCKS_PER_S + c;
    unsigned* candA = wsu + CANDA_OFF + (size_t)blk * CAP;
    unsigned* candB = wsu + CANDB_OFF + (size_t)blk * CAP;
#pragma unroll
    for (int e = 0; e < 16; ++e) {
        unsigned b = o[e] >> 22;
        if ((tmask >> e) & 1u) {
            unsigned bb = b ^ 1023u;
            if ((int)bb >= btB) { int pos = atomicAdd(&shCntB, 1); if (pos < CAP) candB[pos] = ~o[e]; }
        } else {
            if ((int)b >= btA) { int pos = atomicAdd(&shCntA, 1); if (pos < CAP) candA[pos] = o[e]; }
        }
    }
    __syncthreads();
    int nA = shCntA, nB = shCntB;
    if (nA > CAP) { exact30(o, tmask, 0, candA, tid, lane, wid, sred); nA = TOPK; }
    if (nB > CAP) { exact30(o, tmask, 1, candB, tid, lane, wid, sred); nB = TOPK; }
    if (tid == 0) { wsu[CNTA_OFF + blk] = (unsigned)nA; wsu[CNTB_OFF + blk] = (unsigned)nB; }
}

__global__ __launch_bounds__(256) void passB(float* __restrict__ wsf, float* __restrict__ out) {
    unsigned* wsu = (unsigned*)wsf;
    const int s = blockIdx.x;
    const int tid = threadIdx.x, lane = tid & 63, wid = tid >> 6;

    __shared__ unsigned LA[BLOCKS_PER_S * CAP];  // 24 KB
    __shared__ unsigned LB[BLOCKS_PER_S * CAP];  // 24 KB
    __shared__ int hist[BINS];
    __shared__ int wtot[4];
    __shared__ int cnA[64], pfA[64], cnB[64], pfB[64];
    __shared__ int shNA, shNB, shBt, shChi, shCntBt, shK, shR, shResolved, shDone;
    __shared__ unsigned R[TOPK];
    __shared__ float ntop[TOPK], pv[TOPK], fred[8];

    // wave 0: dice sums; wave 1: A prefix; wave 2: B prefix — concurrent
    if (wid == 0) {
        const float* part = wsf + PART_OFF + (size_t)(s * BLOCKS_PER_S + lane) * 3;
        float sp = part[0], st = part[1], spt = part[2];
        for (int off = 32; off; off >>= 1) {
            sp  += __shfl_xor(sp, off, 64);
            st  += __shfl_xor(st, off, 64);
            spt += __shfl_xor(spt, off, 64);
        }
        if (lane == 0) { fred[0] = sp; fred[1] = st; fred[2] = spt; }
    } else if (wid == 1) {
        int cv = (int)wsu[CNTA_OFF + s * BLOCKS_PER_S + lane];
        int pe = cv;
#pragma unroll
        for (int off = 1; off < 64; off <<= 1) {
            int v = __shfl_up(pe, off, 64);
            if (lane >= off) pe += v;
        }
        cnA[lane] = cv; pfA[lane] = pe - cv;
        if (lane == 63) shNA = pe;
    } else if (wid == 2) {
        int cv = (int)wsu[CNTB_OFF + s * BLOCKS_PER_S + lane];
        int pe = cv;
#pragma unroll
        for (int off = 1; off < 64; off <<= 1) {
            int v = __shfl_up(pe, off, 64);
            if (lane >= off) pe += v;
        }
        cnB[lane] = cv; pfB[lane] = pe - cv;
        if (lane == 63) shNB = pe;
    }
    __syncthreads();

    // parallel gather: 4 threads per source block
    {
        const unsigned* gA = wsu + CANDA_OFF + (size_t)s * BLOCKS_PER_S * CAP;
        const unsigned* gB = wsu + CANDB_OFF + (size_t)s * BLOCKS_PER_S * CAP;
        int b = tid >> 2, i0 = tid & 3;
        int na = cnA[b], ofA = pfA[b], nb = cnB[b], ofB = pfB[b];
        for (int i = i0; i < na; i += 4) LA[ofA + i] = gA[b * CAP + i];
        for (int i = i0; i < nb; i += 4) LB[ofB + i] = gB[b * CAP + i];
    }
    __syncthreads();

    for (int arr = 0; arr < 2; ++arr) {
        const unsigned* L = arr ? LB : LA;
        const int n = arr ? shNB : shNA;
        if (tid == 0) { shK = TOPK; shR = 0; shResolved = 0; }
        __syncthreads();

        unsigned prefix = 0u, himask = 0u;
        const int shifts[4] = {22, 12, 2, 0};
        const unsigned bmask[4] = {1023u, 1023u, 1023u, 3u};
#pragma unroll
        for (int lev = 0; lev < 4; ++lev) {
            if (!shResolved) {  // block-uniform
                const int shift = shifts[lev];
                const unsigned bm = bmask[lev];
                for (int i = tid; i < BINS; i += 256) hist[i] = 0;
                __syncthreads();
                for (int i = tid; i < n; i += 256) {
                    unsigned u = L[i];
                    if ((u & himask) == prefix) atomicAdd(&hist[(u >> shift) & bm], 1);
                }
                __syncthreads();
                const int K = shK;
                int c0 = hist[4 * tid], c1 = hist[4 * tid + 1], c2 = hist[4 * tid + 2], c3 = hist[4 * tid + 3];
                int suf = c0 + c1 + c2 + c3;
#pragma unroll
                for (int off = 1; off < 64; off <<= 1) {
                    int v = __shfl_down(suf, off, 64);
                    if (lane + off < 64) suf += v;
                }
                if (lane == 0) wtot[wid] = suf;
                if (tid == 0) shBt = -1;
                __syncthreads();
                int S = suf;
                for (int w = wid + 1; w < 4; ++w) S += wtot[w];
                {
                    int sfx = S;
                    int cc[4] = {c0, c1, c2, c3};
#pragma unroll
                    for (int q = 0; q < 4; ++q) {
                        int cnt = cc[q];
                        if (sfx >= K && sfx - cnt < K) { shBt = 4 * tid + q; shChi = sfx - cnt; shCntBt = cnt; }
                        sfx -= cnt;
                    }
                }
                __syncthreads();
                const int bt = shBt;
                if (bt < 0) {
                    // fewer than K active values: emit them all
                    for (int i = tid; i < n; i += 256) {
                        unsigned u = L[i];
                        if ((u & himask) == prefix) {
                            int pos = atomicAdd(&shR, 1);
                            if (pos < TOPK) R[pos] = u;
                        }
                    }
                    __syncthreads();
                    if (tid == 0) shResolved = 1;
                    __syncthreads();
                } else {
                    const int chi = shChi, cntbt = shCntBt;
                    const int Knew = K - chi;
                    const int finish = (cntbt == Knew) ? 1 : 0;
                    for (int i = tid; i < n; i += 256) {
                        unsigned u = L[i];
                        if ((u & himask) == prefix) {
                            int b_ = (int)((u >> shift) & bm);
                            if (b_ > bt || (finish && b_ == bt)) {
                                int pos = atomicAdd(&shR, 1);
                                R[pos] = u;
                            }
                        }
                    }
                    __syncthreads();
                    if (finish) {
                        if (tid == 0) shResolved = 1;
                    } else if (lev == 3) {
                        // exact-value tie at boundary: append Knew copies
                        unsigned ustar = prefix | (unsigned)bt;
                        if (tid < Knew) { int pos = atomicAdd(&shR, 1); R[pos] = ustar; }
                        if (tid == 0) shResolved = 1;
                    } else {
                        if (tid == 0) shK = Knew;
                        prefix |= ((unsigned)bt << shift);
                        himask |= (bm << shift);
                    }
                    __syncthreads();
                }
            }
        }
        __syncthreads();
        const int rc = shR;
        if (tid < TOPK) {
            unsigned u = (tid < rc) ? R[tid] : 0u;
            float v = invord_sigmoid(u);
            if (arr) pv[tid] = v; else ntop[tid] = v;
        }
        __syncthreads();
    }

    // 30x30 hinge sum
    float rs = 0.f;
    for (int pch = tid; pch < TOPK * TOPK; pch += 256) {
        int i = pch / TOPK, j = pch - i * TOPK;
        float th = ntop[i] - (1.0f - pv[j]) + 0.3f;
        rs += fmaxf(th, 0.0f);
    }
    for (int off = 32; off; off >>= 1) rs += __shfl_xor(rs, off, 64);
    if (lane == 0) fred[4 + wid] = rs;
    __syncthreads();

    if (tid == 0) {
        float SP = fred[0], ST = fred[1], SPT = fred[2];
        float RS = fred[4] + fred[5] + fred[6] + fred[7];
        const float Nf = (float)N_ELEM;
        float dice1 = 1.0f - 2.0f * SPT / (SP + ST + 1e-5f);
        float dice0 = 1.0f - 2.0f * (Nf - SP - ST + SPT) / ((Nf - SP) + (Nf - ST) + 1e-5f);
        float* samp = wsf + SAMP_OFF + s * 2;
        samp[0] = dice0 + dice1;
        samp[1] = RS;
    }
    __threadfence();
    if (tid == 0) shDone = atomicAdd((int*)&wsu[DONE_OFF], 1);
    __syncthreads();
    if (shDone == B_SAMPLES - 1) {
        __threadfence();
        float d = 0.f, r = 0.f;
        if (tid < B_SAMPLES) {
            d = wsf[SAMP_OFF + tid * 2 + 0];
            r = wsf[SAMP_OFF + tid * 2 + 1];
        }
        for (int off = 32; off; off >>= 1) {
            d += __shfl_xor(d, off, 64);
            r += __shfl_xor(r, off, 64);
        }
        if (tid == 0) {
            out[0] = d * (1.0f / (2.0f * B_SAMPLES));
            out[1] = r * (1.0f / (B_SAMPLES * TOPK * TOPK));
        }
    }
}

extern "C" void kernel_launch(void* const* d_in, const int* in_sizes, int n_in,
                              void* d_out, int out_size, void* d_ws, size_t ws_size,
                              hipStream_t stream) {
    (void)in_sizes; (void)n_in; (void)out_size; (void)ws_size;
    const float* pred = (const float*)d_in[0];
    const float* tgt  = (const float*)d_in[1];
    float* wsf = (float*)d_ws;
    float* out = (float*)d_out;

    passA<<<B_SAMPLES * BLOCKS_PER_S, 256, 0, stream>>>(pred, tgt, wsf);
    passB<<<B_SAMPLES, 256, 0, stream>>>(wsf, out);
}